// Round 8
// baseline (49.349 us; speedup 1.0000x reference)
//
#include <hip/hip_runtime.h>

// Continuity loss, neighbor=3, X = (8192, 4096) fp32 row-major.
// loss = -(1/R) * sum_{i=1,2} sum_{j=0,1,2} |X[r,c]X[r+i,c+j]| ln|X[r,c]X[r+i,c+j]|
//
// Identity: u=|x|, w=u*log2(u)  ->  |ab| ln|ab| = ln2*(w_a*u_b + u_a*w_b).
// One v_log_f32 per element-slot; 6 pair terms per base element factor into
// sliding column sums Su/Sw over rows r+1, r+2.
//
// R3: 3-deep raw-register prefetch pipeline -> 29.6 us.
// R4: last-block-done fusion -> 64.8 us REGRESSION. Reverted.
// R5: shfl-down halo -> 51.2 us REGRESSION. Reverted.
// R6: __launch_bounds__(256,4) -> neutral: not occupancy-bound.
// R7: clean/guarded split + no-fmax + PF=4 -> NaN: the zeroed halo lanes
//     (cq==1023, k>=4) hit 0*log2(0) without the clamp. Padding needs the guard.
// R8: R7 but fmaxf guard restored unconditionally (6 v_max/iter, ~4% of body).

constexpr int C  = 4096;
constexpr int CQ = C / 4;   // 1024 quads per row
constexpr int H  = 32;      // base rows per strip
constexpr int NT = 256;
constexpr int PF = 4;       // prefetch depth (raw slots)

template <bool CLEAN>
__device__ __forceinline__ float do_strip(const float* __restrict__ X, int r0, int R,
                                          size_t col, bool halo) {
    float raw[PF][6];
    float u[3][6], w[3][6];

    auto load_row = [&](int rr, float* dst) {
        int rabs = r0 + rr;
        if (!CLEAN) rabs = rabs < R ? rabs : R - 1;    // guarded: clamp, no OOB
        const float* p = X + (size_t)rabs * C + col;
        *reinterpret_cast<float4*>(dst) = *reinterpret_cast<const float4*>(p);
        const float* ph = halo ? p + 4 : X;            // safe dummy addr for last quad
        float2 h = *reinterpret_cast<const float2*>(ph);
        dst[4] = h.x;
        dst[5] = h.y;
    };

    auto uw_row = [&](const float* src, float* uu, float* ww, bool valid) {
#pragma unroll
        for (int k = 0; k < 6; ++k) {
            float a = fabsf(src[k]);
            if (k >= 4 && !halo) a = 0.0f;             // last-quad halo is out of range
            if (!CLEAN && !valid) a = 0.0f;            // rows >= R contribute nothing
            uu[k] = a;
            // fmax guard is REQUIRED: zeroed halo/row lanes would give
            // 0*log2(0) = NaN without it (R7 failure). a==0 -> w==0 with it.
            ww[k] = a * __log2f(fmaxf(a, 1e-37f));
        }
    };

    // prologue: issue rows 0..3, convert 0,1, then issue 4,5.
    // slot(m) = m % 4; consume row rr+2 at iter rr, refill with row rr+6 (same slot).
    load_row(0, raw[0]);
    load_row(1, raw[1]);
    load_row(2, raw[2]);
    load_row(3, raw[3]);
    uw_row(raw[0], u[0], w[0], true);   // r0, r0+1 always < R
    uw_row(raw[1], u[1], w[1], true);
    load_row(4, raw[0]);
    load_row(5, raw[1]);

    float acc = 0.0f;
#pragma unroll
    for (int rr = 0; rr < H; ++rr) {
        const int i0 = rr % 3, i1 = (rr + 1) % 3, i2 = (rr + 2) % 3;  // static
        const int s = (rr + 2) % PF;
        uw_row(raw[s], u[i2], w[i2], r0 + rr + 2 < R);
        if (rr + 6 <= H + 1) load_row(rr + 6, raw[s]);

        float csu[6], csw[6];
#pragma unroll
        for (int k = 0; k < 6; ++k) {
            csu[k] = u[i1][k] + u[i2][k];
            csw[k] = w[i1][k] + w[i2][k];
        }
#pragma unroll
        for (int k = 0; k < 4; ++k) {
            float Su = csu[k] + csu[k + 1] + csu[k + 2];
            float Sw = csw[k] + csw[k + 1] + csw[k + 2];
            acc = fmaf(w[i0][k], Su, fmaf(u[i0][k], Sw, acc));
        }
    }
    return acc;
}

__global__ __launch_bounds__(NT, 4) void closs_partial(const float* __restrict__ X,
                                                       float* __restrict__ part, int R) {
    const int cq  = (blockIdx.x & 3) * NT + threadIdx.x;  // 0..1023
    const int r0  = (blockIdx.x >> 2) * H;
    const bool halo = (cq < CQ - 1);
    const size_t col = (size_t)cq << 2;

    float acc;
    if (r0 + H + 2 <= R) {               // strip touches rows <= r0+H+1 only
        acc = do_strip<true>(X, r0, R, col, halo);
    } else {
        acc = do_strip<false>(X, r0, R, col, halo);
    }

    // wave shuffle reduction + LDS across 4 waves
#pragma unroll
    for (int off = 32; off > 0; off >>= 1) acc += __shfl_down(acc, off, 64);
    __shared__ float wsum[NT / 64];
    const int lane = threadIdx.x & 63;
    const int wid  = threadIdx.x >> 6;
    if (lane == 0) wsum[wid] = acc;
    __syncthreads();
    if (threadIdx.x == 0) {
        float s = 0.0f;
#pragma unroll
        for (int ww = 0; ww < NT / 64; ++ww) s += wsum[ww];
        part[blockIdx.x] = s;
    }
}

__global__ __launch_bounds__(256) void closs_final(const float* __restrict__ part,
                                                   float* __restrict__ out, int n,
                                                   double scale) {
    double s = 0.0;
    for (int i = threadIdx.x; i < n; i += 256) s += (double)part[i];
#pragma unroll
    for (int off = 32; off > 0; off >>= 1) s += __shfl_down(s, off, 64);
    __shared__ double wsum[4];
    const int lane = threadIdx.x & 63;
    const int wid  = threadIdx.x >> 6;
    if (lane == 0) wsum[wid] = s;
    __syncthreads();
    if (threadIdx.x == 0) {
        double t = wsum[0] + wsum[1] + wsum[2] + wsum[3];
        out[0] = (float)(t * scale);
    }
}

extern "C" void kernel_launch(void* const* d_in, const int* in_sizes, int n_in,
                              void* d_out, int out_size, void* d_ws, size_t ws_size,
                              hipStream_t stream) {
    const float* X = (const float*)d_in[0];
    const int R = in_sizes[0] / C;            // 8192
    const int nblocks = (R / H) * (CQ / NT);  // 256 * 4 = 1024

    float* part = (float*)d_ws;               // nblocks floats

    closs_partial<<<nblocks, NT, 0, stream>>>(X, part, R);

    const double scale = -0.69314718055994530942 / (double)R;
    closs_final<<<1, 256, 0, stream>>>(part, (float*)d_out, nblocks, scale);
}

// Round 9
// 30.754 us; speedup vs baseline: 1.6046x; 1.6046x over previous
//
#include <hip/hip_runtime.h>

// Continuity loss, neighbor=3, X = (8192, 4096) fp32 row-major.
// loss = -(1/R) * sum_{i=1,2} sum_{j=0,1,2} |X[r,c]X[r+i,c+j]| ln|X[r,c]X[r+i,c+j]|
//
// Identity: u=|x|, w=u*log2(u)  ->  |ab| ln|ab| = ln2*(w_a*u_b + u_a*w_b).
// One v_log_f32 per element-slot; 6 pair terms factor into sliding column
// sums Su/Sw over rows r+1, r+2.
//
// R3: 3-deep raw-register prefetch pipeline -> 29.6 us (VGPR ~140).
// R4: last-block-done fusion -> 64.8 us REGRESSION. Reverted.
// R5: shfl-down halo -> 51.2 us REGRESSION. Reverted.
// R6: __launch_bounds__(256,4) at PF=3 -> neutral (cap fit).
// R7: no-fmax -> NaN (zeroed halo lanes hit 0*log2(0)). Guard is load-bearing.
// R8: PF=4 + split + cap -> 49.3 us REGRESSION: VGPR collapsed to 64 (cap
//     couldn't fit the pipeline; allocator serialized the loads).
// R9: R8 WITHOUT the min-waves cap — the register pipeline is the kernel;
//     never constrain the allocator below what it needs (~146 VGPR).

constexpr int C  = 4096;
constexpr int CQ = C / 4;   // 1024 quads per row
constexpr int H  = 32;      // base rows per strip
constexpr int NT = 256;
constexpr int PF = 4;       // prefetch depth (raw slots)

template <bool CLEAN>
__device__ __forceinline__ float do_strip(const float* __restrict__ X, int r0, int R,
                                          size_t col, bool halo) {
    float raw[PF][6];
    float u[3][6], w[3][6];

    auto load_row = [&](int rr, float* dst) {
        int rabs = r0 + rr;
        if (!CLEAN) rabs = rabs < R ? rabs : R - 1;    // guarded: clamp, no OOB
        const float* p = X + (size_t)rabs * C + col;
        *reinterpret_cast<float4*>(dst) = *reinterpret_cast<const float4*>(p);
        const float* ph = halo ? p + 4 : X;            // safe dummy addr for last quad
        float2 h = *reinterpret_cast<const float2*>(ph);
        dst[4] = h.x;
        dst[5] = h.y;
    };

    auto uw_row = [&](const float* src, float* uu, float* ww, bool valid) {
#pragma unroll
        for (int k = 0; k < 6; ++k) {
            float a = fabsf(src[k]);
            if (k >= 4 && !halo) a = 0.0f;             // last-quad halo is out of range
            if (!CLEAN && !valid) a = 0.0f;            // rows >= R contribute nothing
            uu[k] = a;
            // fmax guard REQUIRED: zeroed halo/row lanes would give
            // 0*log2(0) = NaN without it (R7 failure). a==0 -> w==0 with it.
            ww[k] = a * __log2f(fmaxf(a, 1e-37f));
        }
    };

    // prologue: issue rows 0..3, convert 0,1, then issue 4,5.
    // slot(m) = m % 4; consume row rr+2 at iter rr, refill with row rr+6.
    load_row(0, raw[0]);
    load_row(1, raw[1]);
    load_row(2, raw[2]);
    load_row(3, raw[3]);
    uw_row(raw[0], u[0], w[0], true);   // r0, r0+1 always < R
    uw_row(raw[1], u[1], w[1], true);
    load_row(4, raw[0]);
    load_row(5, raw[1]);

    float acc = 0.0f;
#pragma unroll
    for (int rr = 0; rr < H; ++rr) {
        const int i0 = rr % 3, i1 = (rr + 1) % 3, i2 = (rr + 2) % 3;  // static
        const int s = (rr + 2) % PF;
        uw_row(raw[s], u[i2], w[i2], r0 + rr + 2 < R);
        if (rr + 6 <= H + 1) load_row(rr + 6, raw[s]);

        float csu[6], csw[6];
#pragma unroll
        for (int k = 0; k < 6; ++k) {
            csu[k] = u[i1][k] + u[i2][k];
            csw[k] = w[i1][k] + w[i2][k];
        }
#pragma unroll
        for (int k = 0; k < 4; ++k) {
            float Su = csu[k] + csu[k + 1] + csu[k + 2];
            float Sw = csw[k] + csw[k + 1] + csw[k + 2];
            acc = fmaf(w[i0][k], Su, fmaf(u[i0][k], Sw, acc));
        }
    }
    return acc;
}

__global__ __launch_bounds__(NT) void closs_partial(const float* __restrict__ X,
                                                    float* __restrict__ part, int R) {
    const int cq  = (blockIdx.x & 3) * NT + threadIdx.x;  // 0..1023
    const int r0  = (blockIdx.x >> 2) * H;
    const bool halo = (cq < CQ - 1);
    const size_t col = (size_t)cq << 2;

    float acc;
    if (r0 + H + 2 <= R) {               // strip touches rows <= r0+H+1 only
        acc = do_strip<true>(X, r0, R, col, halo);
    } else {
        acc = do_strip<false>(X, r0, R, col, halo);
    }

    // wave shuffle reduction + LDS across 4 waves
#pragma unroll
    for (int off = 32; off > 0; off >>= 1) acc += __shfl_down(acc, off, 64);
    __shared__ float wsum[NT / 64];
    const int lane = threadIdx.x & 63;
    const int wid  = threadIdx.x >> 6;
    if (lane == 0) wsum[wid] = acc;
    __syncthreads();
    if (threadIdx.x == 0) {
        float s = 0.0f;
#pragma unroll
        for (int ww = 0; ww < NT / 64; ++ww) s += wsum[ww];
        part[blockIdx.x] = s;
    }
}

__global__ __launch_bounds__(256) void closs_final(const float* __restrict__ part,
                                                   float* __restrict__ out, int n,
                                                   double scale) {
    double s = 0.0;
    for (int i = threadIdx.x; i < n; i += 256) s += (double)part[i];
#pragma unroll
    for (int off = 32; off > 0; off >>= 1) s += __shfl_down(s, off, 64);
    __shared__ double wsum[4];
    const int lane = threadIdx.x & 63;
    const int wid  = threadIdx.x >> 6;
    if (lane == 0) wsum[wid] = s;
    __syncthreads();
    if (threadIdx.x == 0) {
        double t = wsum[0] + wsum[1] + wsum[2] + wsum[3];
        out[0] = (float)(t * scale);
    }
}

extern "C" void kernel_launch(void* const* d_in, const int* in_sizes, int n_in,
                              void* d_out, int out_size, void* d_ws, size_t ws_size,
                              hipStream_t stream) {
    const float* X = (const float*)d_in[0];
    const int R = in_sizes[0] / C;            // 8192
    const int nblocks = (R / H) * (CQ / NT);  // 256 * 4 = 1024

    float* part = (float*)d_ws;               // nblocks floats

    closs_partial<<<nblocks, NT, 0, stream>>>(X, part, R);

    const double scale = -0.69314718055994530942 / (double)R;
    closs_final<<<1, 256, 0, stream>>>(part, (float*)d_out, nblocks, scale);
}